// Round 10
// baseline (928.885 us; speedup 1.0000x reference)
//
#include <hip/hip_runtime.h>
#include <math.h>

typedef unsigned short u16;
typedef unsigned int u32;

#define B_ 2
#define T_ 4096
#define DM 512
#define NH 8
#define DH 64
#define DFF 2048
#define MTOT (B_*T_)   // 8192

// Q pre-scale: (1/sqrt(64)) * log2(e)  -> softmax runs in exp2 domain
#define SCALEQ 0.18033688011112042f

using f32x4  = __attribute__((ext_vector_type(4))) float;
using f32x16 = __attribute__((ext_vector_type(16))) float;
using bf16x8 = __attribute__((ext_vector_type(8))) short;
typedef unsigned int u32x2 __attribute__((ext_vector_type(2)));

__device__ __forceinline__ float b2f(u16 u) {
  union { u32 u; float f; } v; v.u = ((u32)u) << 16; return v.f;
}
__device__ __forceinline__ u16 f2b(float f) {
  union { float f; u32 u; } v; v.f = f;
  u32 r = v.u + 0x7FFFu + ((v.u >> 16) & 1u);
  return (u16)(r >> 16);
}
// packed f32 pair -> bf16 pair (RTNE), single VALU op
__device__ __forceinline__ u32 cvtpk(float lo, float hi) {
  u32 r;
  asm("v_cvt_pk_bf16_f32 %0, %1, %2" : "=v"(r) : "v"(lo), "v"(hi));
  return r;
}
#if __has_builtin(__builtin_amdgcn_exp2f)
#define EXP2(x) __builtin_amdgcn_exp2f(x)
#else
#define EXP2(x) __expf((x) * 0.6931471805599453f)
#endif
#if __has_builtin(__builtin_amdgcn_rcpf)
#define RCP(x) __builtin_amdgcn_rcpf(x)
#else
#define RCP(x) (1.0f / (x))
#endif

// async global->LDS, 16B per lane, dest = uniform base + lane*16
__device__ __forceinline__ void gload_lds(const u16* g, u16* l) {
  __builtin_amdgcn_global_load_lds(
      (const __attribute__((address_space(1))) void*)g,
      (__attribute__((address_space(3))) void*)l, 16, 0, 0);
}

// LDS swizzle for [64][64] u16 tiles (128B rows). Returns u16 element offset.
__device__ __forceinline__ int lsw(int row, int col) {
  int slot = ((col >> 3) + (row >> 3) + 2 * (row & 7)) & 7;
  return (row << 6) + (slot << 3) + (col & 7);
}

// ---------------- embed ----------------
__global__ __launch_bounds__(256) void embed_k(
    const float* __restrict__ x_in, const float* __restrict__ w,
    const float* __restrict__ bias, const float* __restrict__ pos,
    float* __restrict__ x) {
  int idx = blockIdx.x * 256 + threadIdx.x;
  int row = idx >> 9, d = idx & 511;
  int t = row & (T_ - 1);
  x[idx] = x_in[row] * w[d] + bias[d] + pos[t * DM + d];
}

// ------- layernorm (+ optional NP bf16 split-K partial-adds into x) ---------
template<int NP>
__global__ __launch_bounds__(256) void ln_k(
    float* __restrict__ x, const u16* __restrict__ P,
    const float* __restrict__ g, const float* __restrict__ bet,
    u16* __restrict__ y) {
  int wid = threadIdx.x >> 6, lane = threadIdx.x & 63;
  int row = blockIdx.x * 4 + wid;
  float* xr = x + (size_t)row * DM + lane * 8;
  float4 a0 = *(const float4*)xr;
  float4 a1 = *(const float4*)(xr + 4);
  float v[8] = {a0.x, a0.y, a0.z, a0.w, a1.x, a1.y, a1.z, a1.w};
  if (NP > 0) {
#pragma unroll
    for (int s = 0; s < NP; s++) {
      const u16* pr = P + (size_t)s * MTOT * DM + (size_t)row * DM + lane * 8;
      uint4 pv = *(const uint4*)pr;
      const u16* px = (const u16*)&pv;
#pragma unroll
      for (int j = 0; j < 8; j++) v[j] += b2f(px[j]);
    }
    float4 w0; w0.x = v[0]; w0.y = v[1]; w0.z = v[2]; w0.w = v[3];
    float4 w1; w1.x = v[4]; w1.y = v[5]; w1.z = v[6]; w1.w = v[7];
    *(float4*)xr = w0;
    *(float4*)(xr + 4) = w1;
  }
  float s = 0.f;
#pragma unroll
  for (int j = 0; j < 8; j++) s += v[j];
#pragma unroll
  for (int off = 32; off; off >>= 1) s += __shfl_xor(s, off);
  float mu = s * (1.0f / DM);
  float q = 0.f;
#pragma unroll
  for (int j = 0; j < 8; j++) { float e = v[j] - mu; q += e * e; }
#pragma unroll
  for (int off = 32; off; off >>= 1) q += __shfl_xor(q, off);
  float rs = rsqrtf(q * (1.0f / DM) + 1e-5f);
  float4 g0 = *(const float4*)(g + lane * 8);
  float4 g1 = *(const float4*)(g + lane * 8 + 4);
  float4 p0 = *(const float4*)(bet + lane * 8);
  float4 p1 = *(const float4*)(bet + lane * 8 + 4);
  float gg[8] = {g0.x, g0.y, g0.z, g0.w, g1.x, g1.y, g1.z, g1.w};
  float pp[8] = {p0.x, p0.y, p0.z, p0.w, p1.x, p1.y, p1.z, p1.w};
  uint4 st;
  st.x = cvtpk((v[0]-mu)*rs*gg[0]+pp[0], (v[1]-mu)*rs*gg[1]+pp[1]);
  st.y = cvtpk((v[2]-mu)*rs*gg[2]+pp[2], (v[3]-mu)*rs*gg[3]+pp[3]);
  st.z = cvtpk((v[4]-mu)*rs*gg[4]+pp[4], (v[5]-mu)*rs*gg[5]+pp[5]);
  st.w = cvtpk((v[6]-mu)*rs*gg[6]+pp[6], (v[7]-mu)*rs*gg[7]+pp[7]);
  *(uint4*)(y + (size_t)row * DM + lane * 8) = st;
}

// ---------------- weight convert+transpose: W[K][N] fp32 -> Wt[N][K] bf16 ----
__global__ __launch_bounds__(256) void wconv_k(
    const float* __restrict__ W, u16* __restrict__ Wt, int K, int N) {
  __shared__ float tile[32][33];
  const float* Wl = W + (size_t)blockIdx.z * K * N;
  u16* Wtl = Wt + (size_t)blockIdx.z * K * N;
  int k0 = blockIdx.x * 32, n0 = blockIdx.y * 32;
  int r = threadIdx.x >> 3, c4 = (threadIdx.x & 7) * 4;
  *(float4*)&tile[r][c4] = *(const float4*)(Wl + (size_t)(k0 + r) * N + n0 + c4);
  __syncthreads();
  uint2 st;
  st.x = cvtpk(tile[c4 + 0][r], tile[c4 + 1][r]);
  st.y = cvtpk(tile[c4 + 2][r], tile[c4 + 3][r]);
  *(uint2*)(Wtl + (size_t)(n0 + r) * K + k0 + c4) = st;
}

// ---------------- bf16 MFMA GEMM: C[M,N] = A[M,K] @ Bt[N,K]^T ----------------
// R7 structure: 2-buffer global_load_lds staging, one __syncthreads per step.
// XCD-bijective block swizzle (all grids have nwg%8==0).
// EPI: 0 = bf16 store (cols<scale_cols *= SCALEQ), 1 = Cf += acc,
// 2 = gelu->bf16, 4 = bf16 split-K partial (Cb + z*M*N).
template<int EPI>
__global__ __launch_bounds__(256) void gemm_k(
    const u16* __restrict__ A, const u16* __restrict__ Bt,
    u16* __restrict__ Cb, float* __restrict__ Cf,
    int M, int N, int K, int Kslice, int scale_cols) {
  __shared__ u16 As[2][128][32];
  __shared__ u16 Bs[2][128][32];   // Bs[buf][n][k]
  int tid = threadIdx.x;
  int lane = tid & 63, wid = tid >> 6;
  int wr = wid >> 1, wc = wid & 1;
  // XCD swizzle: contiguous chunk of blocks per XCD (bijective, nwg%8==0)
  int nwg = gridDim.x * gridDim.y;
  int flat = blockIdx.y * gridDim.x + blockIdx.x;
  int swz = (flat & 7) * (nwg >> 3) + (flat >> 3);
  int bx = swz % gridDim.x, by = swz / gridDim.x;
  int m0 = by * 128, n0 = bx * 128;
  int kbeg = blockIdx.z * Kslice;
  if (EPI == 4) Cb += (size_t)blockIdx.z * M * N;
  f32x4 acc[4][4] = {};
  int rsub = lane >> 2, ksub = (lane & 3) * 8;
  const u16* Ab = A  + (size_t)(m0 + wid * 32 + rsub) * K + kbeg + ksub;
  const u16* Bb = Bt + (size_t)(n0 + wid * 32 + rsub) * K + kbeg + ksub;
#define GSTAGE(BUF, KO) { \
    gload_lds(Ab + (KO), &As[BUF][wid * 32][0]); \
    gload_lds(Ab + (size_t)16 * K + (KO), &As[BUF][wid * 32 + 16][0]); \
    gload_lds(Bb + (KO), &Bs[BUF][wid * 32][0]); \
    gload_lds(Bb + (size_t)16 * K + (KO), &Bs[BUF][wid * 32 + 16][0]); }
  GSTAGE(0, 0);
  __syncthreads();
  int r = lane & 15, kc = (lane >> 4) * 8;
  for (int k0 = 0; k0 < Kslice; k0 += 32) {
    int cur = (k0 >> 5) & 1;
    if (k0 + 32 < Kslice) GSTAGE(cur ^ 1, k0 + 32);
    bf16x8 af[4], bfr[4];
#pragma unroll
    for (int m = 0; m < 4; m++) af[m]  = *(const bf16x8*)&As[cur][wr*64 + m*16 + r][kc];
#pragma unroll
    for (int n = 0; n < 4; n++) bfr[n] = *(const bf16x8*)&Bs[cur][wc*64 + n*16 + r][kc];
#pragma unroll
    for (int m = 0; m < 4; m++)
#pragma unroll
      for (int n = 0; n < 4; n++)
        acc[m][n] = __builtin_amdgcn_mfma_f32_16x16x32_bf16(af[m], bfr[n], acc[m][n], 0, 0, 0);
    __syncthreads();
  }
  int r4 = (lane >> 4) * 4, cN = lane & 15;
#pragma unroll
  for (int m = 0; m < 4; m++) {
#pragma unroll
    for (int n = 0; n < 4; n++) {
      int col = n0 + wc*64 + n*16 + cN;
#pragma unroll
      for (int i = 0; i < 4; i++) {
        int row = m0 + wr*64 + m*16 + r4 + i;
        size_t off = (size_t)row * N + col;
        float v = acc[m][n][i];
        if (EPI == 0) {
          if (col < scale_cols) v *= SCALEQ;
          Cb[off] = f2b(v);
        } else if (EPI == 1) {
          Cf[off] += v;
        } else if (EPI == 4) {
          Cb[off] = f2b(v);
        } else {
          float e = EXP2(v * (2.3022082f + 0.10294324f * v * v));
          Cb[off] = f2b(v * (1.0f - RCP(e + 1.0f)));
        }
      }
    }
  }
}

// permlane32_swap: one instr yields BOTH PV fragment words for a lane-half pair
#if __has_builtin(__builtin_amdgcn_permlane32_swap)
#define PLSWAP(A, B, O0, O1) { \
    u32x2 r_ = __builtin_amdgcn_permlane32_swap((A), (B), false, false); \
    O0 = r_.x; O1 = r_.y; }
#else
#define PLSWAP(A, B, O0, O1) { \
    u32 as_ = __shfl_xor((u32)(A), 32), bs_ = __shfl_xor((u32)(B), 32); \
    O0 = hh ? bs_ : (A); O1 = hh ? (B) : as_; }
#endif

// ---------------- MFMA causal flash attention, uniform 8-tile chunks --------
// R7 sync structure (one __syncthreads/tile). K staged via global_load_lds
// with PRE-SWIZZLED global source (verified R6/R8) - saves 8 staging VGPRs.
// V reg-staged; AGV issued after softmax (short vreg live range).
// Target: natural VGPR <= 102 -> 5 blocks/CU (LDS 32KB allows exactly 5).
__global__ __launch_bounds__(256) void attn_k(const u16* __restrict__ qkv,
                                              u16* __restrict__ Opart,
                                              float* __restrict__ ml) {
  __shared__ u16 Ks[2][64 * 64];
  __shared__ u16 Vt[2][64 * 64];
  int tid = threadIdx.x;
  int w = tid >> 6, l = tid & 63;
  int hh = l >> 5, c = l & 31;
  int flat = blockIdx.y * 144 + blockIdx.x;
  int swz = (flat & 7) * 288 + (flat >> 3);      // 2304/8 = 288
  int bh = swz / 144, slot = swz - bh * 144;
  int g = 0;
  while (2 * (g + 1) * (g + 2) <= slot) g++;     // group index 0..7
  int s2 = slot - 2 * g * (g + 1);
  int qb = 4 * g + s2 / (g + 1);
  int ck = s2 - (s2 / (g + 1)) * (g + 1);
  int ntot = 2 * qb + 2;
  int kt0 = ck * 8;
  int kt1 = kt0 + 8 < ntot ? kt0 + 8 : ntot;
  int b = bh >> 3, hd = bh & 7;
  int q0w = qb * 128 + w * 32;
  int q_abs = q0w + c;
  size_t base = (size_t)b * T_ * 1536;
  bf16x8 qf[4];
  const u16* qp = qkv + base + (size_t)q_abs * 1536 + hd * 64 + hh * 8;
#pragma unroll
  for (int kk = 0; kk < 4; kk++) qf[kk] = *(const bf16x8*)(qp + kk * 16);
  f32x16 oa0 = {}, oa1 = {};
  float m_run = -1e30f, l_run = 0.f;
  const u16* kvb = qkv + base + DM + hd * 64;
  // K gload pre-swizzled source: lane (lr,ls); wave w covers rows w*8.. and
  // (w+4)*8..; fetched col-group compensates lsw so LDS reads use lsw().
  int lr = l >> 3, ls = l & 7;
  int rA = w * 8 + lr;
  int rB = (w + 4) * 8 + lr;
  int cA = ((ls - w - 2 * (rA & 7)) & 7) * 8;
  int cB = ((ls - (w + 4) - 2 * (rB & 7)) & 7) * 8;
  const u16* ksrcA = kvb + (size_t)rA * 1536 + cA;
  const u16* ksrcB = kvb + (size_t)rB * 1536 + cB;
  // V reg staging: rows r0,r0+1, cols d8..d8+7
  int sp = tid >> 3, d8 = (tid & 7) * 8;
  int r0 = sp * 2;
  uint4 vreg0, vreg1;
#define KGLOAD(KT) { \
    size_t ko_ = (size_t)(KT) * 64 * 1536; int nx_ = (KT) & 1; \
    gload_lds(ksrcA + ko_, &Ks[nx_][w * 512]); \
    gload_lds(ksrcB + ko_, &Ks[nx_][(w + 4) * 512]); }
#define AGV(KT) { \
    const u16* s_ = kvb + DM + (size_t)((KT) * 64 + r0) * 1536 + d8; \
    vreg0 = *(const uint4*)s_; vreg1 = *(const uint4*)(s_ + 1536); }
  KGLOAD(kt0);
  AGV(kt0);
  for (int kt = kt0; kt < kt1; kt++) {
    int cur = kt & 1;
    bool more = (kt + 1 < kt1);
    {  // transpose-write V(kt) into Vt[cur] (compiler waits vreg loads)
      u16* Vb = Vt[cur];
      const u16* v0 = (const u16*)&vreg0;
      const u16* v1 = (const u16*)&vreg1;
#pragma unroll
      for (int j = 0; j < 8; j++) {
        u32 pw = (u32)v0[j] | ((u32)v1[j] << 16);
        *(u32*)&Vb[lsw(d8 + j, r0)] = pw;
      }
    }
    __syncthreads();   // drains wave's own K(kt) gload + makes V writes visible
    if (more) KGLOAD(kt + 1);          // lands in Ks[cur^1] under this compute
    if (kt * 64 > q0w + 31) {          // fully masked for this wave
      if (more) AGV(kt + 1);
      continue;
    }
    const u16* Kb = Ks[cur];
    const u16* Vb = Vt[cur];
    bool needMask = (kt * 64 + 63 > q0w);
    f32x16 sa0 = {}, sa1 = {};
    __builtin_amdgcn_s_setprio(1);
#pragma unroll
    for (int kk = 0; kk < 4; kk++) {
      bf16x8 ka  = *(const bf16x8*)&Kb[lsw(c,      kk * 16 + hh * 8)];
      bf16x8 kb2 = *(const bf16x8*)&Kb[lsw(32 + c, kk * 16 + hh * 8)];
      sa0 = __builtin_amdgcn_mfma_f32_32x32x16_bf16(ka,  qf[kk], sa0, 0, 0, 0);
      sa1 = __builtin_amdgcn_mfma_f32_32x32x16_bf16(kb2, qf[kk], sa1, 0, 0, 0);
    }
    __builtin_amdgcn_s_setprio(0);
    if (needMask) {
#pragma unroll
      for (int gi = 0; gi < 4; gi++)
#pragma unroll
        for (int i = 0; i < 4; i++) {
          int krow = kt * 64 + gi * 8 + hh * 4 + i;
          if (krow > q_abs)      sa0[gi * 4 + i] = -1e30f;
          if (krow + 32 > q_abs) sa1[gi * 4 + i] = -1e30f;
        }
    }
    // max tree (depth ~5)
    float t[8];
#pragma unroll
    for (int r = 0; r < 8; r++)
      t[r] = fmaxf(fmaxf(sa0[r], sa0[r + 8]), fmaxf(sa1[r], sa1[r + 8]));
    float pm = fmaxf(fmaxf(fmaxf(t[0], t[1]), fmaxf(t[2], t[3])),
                     fmaxf(fmaxf(t[4], t[5]), fmaxf(t[6], t[7])));
    pm = fmaxf(pm, __shfl_xor(pm, 32));
    if (!__all(pm - m_run <= 8.0f)) {
      float mnew = fmaxf(m_run, pm);
      float corr = EXP2(m_run - mnew);
      l_run *= corr;
#pragma unroll
      for (int r = 0; r < 16; r++) { oa0[r] *= corr; oa1[r] *= corr; }
      m_run = mnew;
    }
    float sarr[16];
#pragma unroll
    for (int r = 0; r < 16; r++) {
      float e0 = EXP2(sa0[r] - m_run); sa0[r] = e0;
      float e1 = EXP2(sa1[r] - m_run); sa1[r] = e1;
      sarr[r] = e0 + e1;
    }
#pragma unroll
    for (int r = 0; r < 8; r++) sarr[r] += sarr[r + 8];
#pragma unroll
    for (int r = 0; r < 4; r++) sarr[r] += sarr[r + 4];
    float lsum = (sarr[0] + sarr[1]) + (sarr[2] + sarr[3]);
    lsum += __shfl_xor(lsum, 32);
    l_run += lsum;
    // pack P^T -> bf16 words (sa dies here)
    u32 Aw[8], Bw_[8];
#pragma unroll
    for (int r2 = 0; r2 < 4; r2++) {
      Aw[r2]      = cvtpk(sa0[4 * r2 + 0], sa0[4 * r2 + 1]);
      Bw_[r2]     = cvtpk(sa0[4 * r2 + 2], sa0[4 * r2 + 3]);
      Aw[4 + r2]  = cvtpk(sa1[4 * r2 + 0], sa1[4 * r2 + 1]);
      Bw_[4 + r2] = cvtpk(sa1[4 * r2 + 2], sa1[4 * r2 + 3]);
    }
    if (more) AGV(kt + 1);   // V(kt+1) loads fly under the PV phase
    // O^T += V^T . P^T   (permlane32_swap builds both fragment halves)
    __builtin_amdgcn_s_setprio(1);
#pragma unroll
    for (int ks = 0; ks < 4; ks++) {
      int mo = (ks >> 1) * 4;
      int r2e = mo + 2 * (ks & 1), r2o = r2e + 1;
      union { u32 wd[4]; bf16x8 v; } u;
      PLSWAP(Aw[r2e], Aw[r2o], u.wd[0], u.wd[2]);
      PLSWAP(Bw_[r2e], Bw_[r2o], u.wd[1], u.wd[3]);
      bf16x8 va = *(const bf16x8*)&Vb[lsw(c,      ks * 16 + hh * 8)];
      bf16x8 vb = *(const bf16x8*)&Vb[lsw(32 + c, ks * 16 + hh * 8)];
      oa0 = __builtin_amdgcn_mfma_f32_32x32x16_bf16(va, u.v, oa0, 0, 0, 0);
      oa1 = __builtin_amdgcn_mfma_f32_32x32x16_bf16(vb, u.v, oa1, 0, 0, 0);
    }
    __builtin_amdgcn_s_setprio(0);
  }
  // write unnormalized partial
  int sidx = bh * 144 + slot;
  u16* op = Opart + ((size_t)sidx * 128 + w * 32 + c) * 64;
#pragma unroll
  for (int gi = 0; gi < 4; gi++) {
    uint2 s0, s1;
    s0.x = cvtpk(oa0[4*gi+0], oa0[4*gi+1]);
    s0.y = cvtpk(oa0[4*gi+2], oa0[4*gi+3]);
    s1.x = cvtpk(oa1[4*gi+0], oa1[4*gi+1]);
    s1.y = cvtpk(oa1[4*gi+2], oa1[4*gi+3]);
    int d0 = gi * 8 + hh * 4;
    *(uint2*)(op + d0)      = s0;
    *(uint2*)(op + 32 + d0) = s1;
  }
  if (hh == 0) {
    float2 p; p.x = m_run; p.y = l_run;
    *(float2*)&ml[((size_t)sidx * 128 + w * 32 + c) * 2] = p;
  }
}

// ---------------- combine partials -> attno (4 d-elems per thread) ----------
__global__ __launch_bounds__(256) void comb_k(
    const u16* __restrict__ Opart, const float* __restrict__ ml,
    u16* __restrict__ attno) {
  int gi = blockIdx.x * 256 + threadIdx.x;     // over 16*4096*16
  int d4 = (gi & 15) * 4;
  int bhq = gi >> 4;
  int bh = bhq >> 12, q = bhq & 4095;
  int qb = q >> 7, ri = q & 127;
  int g = qb >> 2;
  int nc = g + 1;
  int bs = 2 * g * (g + 1) + (qb & 3) * (g + 1);
  int s0 = bh * 144 + bs;
  float M = -1e30f;
  for (int cc = 0; cc < nc; cc++)
    M = fmaxf(M, ml[((size_t)(s0 + cc) * 128 + ri) * 2]);
  float O0 = 0.f, O1 = 0.f, O2 = 0.f, O3 = 0.f, L = 0.f;
  for (int cc = 0; cc < nc; cc++) {
    float2 p = *(const float2*)&ml[((size_t)(s0 + cc) * 128 + ri) * 2];
    float wgt = EXP2(p.x - M);
    L += p.y * wgt;
    uint2 ov = *(const uint2*)&Opart[((size_t)(s0 + cc) * 128 + ri) * 64 + d4];
    const u16* opx = (const u16*)&ov;
    O0 += b2f(opx[0]) * wgt; O1 += b2f(opx[1]) * wgt;
    O2 += b2f(opx[2]) * wgt; O3 += b2f(opx[3]) * wgt;
  }
  float invL = 1.0f / L;
  int b = bh >> 3, hd = bh & 7;
  uint2 st;
  st.x = cvtpk(O0 * invL, O1 * invL);
  st.y = cvtpk(O2 * invL, O3 * invL);
  *(uint2*)&attno[((size_t)b * T_ + q) * DM + hd * 64 + d4] = st;
}

// ---------------- head: out = lnf(bf16) @ head_w + head_b, N=64 ----------------
__global__ __launch_bounds__(256) void head_k(
    const u16* __restrict__ xb, const float* __restrict__ W,
    const float* __restrict__ bias, float* __restrict__ out) {
  int wid = threadIdx.x >> 6, lane = threadIdx.x & 63;
  int row = blockIdx.x * 4 + wid;
  const u16* xr = xb + (size_t)row * DM;
  float a0 = 0.f, a1 = 0.f, a2 = 0.f, a3 = 0.f;
  for (int d = 0; d < DM; d += 8) {
    uint4 xv = *(const uint4*)(xr + d);
    const u16* xp = (const u16*)&xv;
    const float* Wp = W + (size_t)d * 64 + lane;
    a0 += b2f(xp[0]) * Wp[0];
    a1 += b2f(xp[1]) * Wp[64];
    a2 += b2f(xp[2]) * Wp[128];
    a3 += b2f(xp[3]) * Wp[192];
    a0 += b2f(xp[4]) * Wp[256];
    a1 += b2f(xp[5]) * Wp[320];
    a2 += b2f(xp[6]) * Wp[384];
    a3 += b2f(xp[7]) * Wp[448];
  }
  out[(size_t)row * 64 + lane] = a0 + a1 + a2 + a3 + bias[lane];
}

extern "C" void kernel_launch(void* const* d_in, const int* in_sizes, int n_in,
                              void* d_out, int out_size, void* d_ws, size_t ws_size,
                              hipStream_t stream) {
  (void)in_sizes; (void)n_in; (void)out_size; (void)ws_size;
  const float* x_in  = (const float*)d_in[0];
  const float* inp_w = (const float*)d_in[1];
  const float* inp_b = (const float*)d_in[2];
  const float* pos   = (const float*)d_in[3];
  const float* ln1g  = (const float*)d_in[4];
  const float* ln1b  = (const float*)d_in[5];
  const float* qkvw  = (const float*)d_in[6];
  const float* projw = (const float*)d_in[7];
  const float* ln2g  = (const float*)d_in[8];
  const float* ln2b  = (const float*)d_in[9];
  const float* fc1w  = (const float*)d_in[10];
  const float* fc2w  = (const float*)d_in[11];
  const float* lnfg  = (const float*)d_in[12];
  const float* lnfb  = (const float*)d_in[13];
  const float* headw = (const float*)d_in[14];
  const float* headb = (const float*)d_in[15];

  char* ws = (char*)d_ws;
  size_t off = 0;
  float* x     = (float*)(ws + off); off += (size_t)MTOT * DM * 4;
  u16*  lnb    = (u16*)(ws + off);   off += (size_t)MTOT * DM * 2;
  u16*  qkvb   = (u16*)(ws + off);   off += (size_t)MTOT * 3 * DM * 2;
  u16*  attno  = (u16*)(ws + off);   off += (size_t)MTOT * DM * 2;
  u16*  ff     = qkvb;  // reuses qkv+attno regions
  u16*  qkvt   = (u16*)(ws + off);   off += (size_t)4 * DM * 3 * DM * 2;
  u16*  projt  = (u16*)(ws + off);   off += (size_t)4 * DM * DM * 2;
  u16*  fc1t   = (u16*)(ws + off);   off += (size_t)4 * DM * DFF * 2;
  u16*  fc2t   = (u16*)(ws + off);   off += (size_t)4 * DFF * DM * 2;
  // shared scratch, time-multiplexed:
  //   attn..comb : Opart (37.75MB) + ml (2.36MB)
  //   proj..ln2  : proj split-K4 bf16 partials (33.6MB)
  //   fc2..ln1'  : fc2  split-K4 bf16 partials (33.6MB)
  char* shared = ws + off;
  u16*  Opart  = (u16*)shared;
  float* mlbuf = (float*)(shared + (size_t)16 * 144 * 128 * 64 * 2);
  u16*  fcp    = (u16*)shared;

  wconv_k<<<dim3(16, 48, 4), 256, 0, stream>>>(qkvw,  qkvt, DM, 3 * DM);
  wconv_k<<<dim3(16, 16, 4), 256, 0, stream>>>(projw, projt, DM, DM);
  wconv_k<<<dim3(16, 64, 4), 256, 0, stream>>>(fc1w,  fc1t, DM, DFF);
  wconv_k<<<dim3(64, 16, 4), 256, 0, stream>>>(fc2w,  fc2t, DFF, DM);

  embed_k<<<(MTOT * DM) / 256, 256, 0, stream>>>(x_in, inp_w, inp_b, pos, x);
  for (int ly = 0; ly < 4; ly++) {
    if (ly == 0)
      ln_k<0><<<MTOT / 4, 256, 0, stream>>>(x, nullptr, ln1g, ln1b, lnb);
    else
      ln_k<4><<<MTOT / 4, 256, 0, stream>>>(x, fcp, ln1g + ly * DM, ln1b + ly * DM, lnb);
    gemm_k<0><<<dim3(12, 64), 256, 0, stream>>>(lnb, qkvt + (size_t)ly * DM * 3 * DM,
                                                qkvb, nullptr, MTOT, 3 * DM, DM, DM, DM);
    attn_k<<<dim3(144, 16), 256, 0, stream>>>(qkvb, Opart, mlbuf);
    comb_k<<<(16 * 4096 * 16) / 256, 256, 0, stream>>>(Opart, mlbuf, attno);
    gemm_k<4><<<dim3(4, 64, 4), 256, 0, stream>>>(attno, projt + (size_t)ly * DM * DM,
                                                  fcp, nullptr, MTOT, DM, DM, DM / 4, 0);
    ln_k<4><<<MTOT / 4, 256, 0, stream>>>(x, fcp, ln2g + ly * DM, ln2b + ly * DM, lnb);
    gemm_k<2><<<dim3(16, 64), 256, 0, stream>>>(lnb, fc1t + (size_t)ly * DM * DFF,
                                                ff, nullptr, MTOT, DFF, DM, DM, 0);
    gemm_k<4><<<dim3(4, 64, 4), 256, 0, stream>>>(ff, fc2t + (size_t)ly * DFF * DM,
                                                  fcp, nullptr, MTOT, DM, DFF, DFF / 4, 0);
  }
  ln_k<4><<<MTOT / 4, 256, 0, stream>>>(x, fcp, lnfg, lnfb, lnb);
  head_k<<<MTOT / 4, 256, 0, stream>>>(lnb, headw, headb, (float*)d_out);
}

// Round 11
// 854.235 us; speedup vs baseline: 1.0874x; 1.0874x over previous
//
#include <hip/hip_runtime.h>
#include <math.h>

typedef unsigned short u16;
typedef unsigned int u32;

#define B_ 2
#define T_ 4096
#define DM 512
#define NH 8
#define DH 64
#define DFF 2048
#define MTOT (B_*T_)   // 8192

// Q pre-scale: (1/sqrt(64)) * log2(e)  -> softmax runs in exp2 domain
#define SCALEQ 0.18033688011112042f

using f32x4  = __attribute__((ext_vector_type(4))) float;
using f32x16 = __attribute__((ext_vector_type(16))) float;
using bf16x8 = __attribute__((ext_vector_type(8))) short;
typedef unsigned int u32x2 __attribute__((ext_vector_type(2)));

__device__ __forceinline__ float b2f(u16 u) {
  union { u32 u; float f; } v; v.u = ((u32)u) << 16; return v.f;
}
__device__ __forceinline__ u16 f2b(float f) {
  union { float f; u32 u; } v; v.f = f;
  u32 r = v.u + 0x7FFFu + ((v.u >> 16) & 1u);
  return (u16)(r >> 16);
}
// packed f32 pair -> bf16 pair (RTNE), single VALU op
__device__ __forceinline__ u32 cvtpk(float lo, float hi) {
  u32 r;
  asm("v_cvt_pk_bf16_f32 %0, %1, %2" : "=v"(r) : "v"(lo), "v"(hi));
  return r;
}
#if __has_builtin(__builtin_amdgcn_exp2f)
#define EXP2(x) __builtin_amdgcn_exp2f(x)
#else
#define EXP2(x) __expf((x) * 0.6931471805599453f)
#endif
#if __has_builtin(__builtin_amdgcn_rcpf)
#define RCP(x) __builtin_amdgcn_rcpf(x)
#else
#define RCP(x) (1.0f / (x))
#endif

// async global->LDS, 16B per lane, dest = uniform base + lane*16
__device__ __forceinline__ void gload_lds(const u16* g, u16* l) {
  __builtin_amdgcn_global_load_lds(
      (const __attribute__((address_space(1))) void*)g,
      (__attribute__((address_space(3))) void*)l, 16, 0, 0);
}

// LDS swizzle for [64][64] u16 tiles (128B rows). Returns u16 element offset.
__device__ __forceinline__ int lsw(int row, int col) {
  int slot = ((col >> 3) + (row >> 3) + 2 * (row & 7)) & 7;
  return (row << 6) + (slot << 3) + (col & 7);
}

// ---- LN body shared by ln_k / embln_k: v[8] per lane -> x row + bf16 row ----
__device__ __forceinline__ void ln_finish(
    float* xr, float v[8], const float* g, const float* bet,
    u16* y, size_t yoff, int lane, bool writeX) {
  if (writeX) {
    float4 w0; w0.x = v[0]; w0.y = v[1]; w0.z = v[2]; w0.w = v[3];
    float4 w1; w1.x = v[4]; w1.y = v[5]; w1.z = v[6]; w1.w = v[7];
    *(float4*)xr = w0;
    *(float4*)(xr + 4) = w1;
  }
  float s = 0.f;
#pragma unroll
  for (int j = 0; j < 8; j++) s += v[j];
#pragma unroll
  for (int off = 32; off; off >>= 1) s += __shfl_xor(s, off);
  float mu = s * (1.0f / DM);
  float q = 0.f;
#pragma unroll
  for (int j = 0; j < 8; j++) { float e = v[j] - mu; q += e * e; }
#pragma unroll
  for (int off = 32; off; off >>= 1) q += __shfl_xor(q, off);
  float rs = rsqrtf(q * (1.0f / DM) + 1e-5f);
  float4 g0 = *(const float4*)(g + lane * 8);
  float4 g1 = *(const float4*)(g + lane * 8 + 4);
  float4 p0 = *(const float4*)(bet + lane * 8);
  float4 p1 = *(const float4*)(bet + lane * 8 + 4);
  float gg[8] = {g0.x, g0.y, g0.z, g0.w, g1.x, g1.y, g1.z, g1.w};
  float pp[8] = {p0.x, p0.y, p0.z, p0.w, p1.x, p1.y, p1.z, p1.w};
  uint4 st;
  st.x = cvtpk((v[0]-mu)*rs*gg[0]+pp[0], (v[1]-mu)*rs*gg[1]+pp[1]);
  st.y = cvtpk((v[2]-mu)*rs*gg[2]+pp[2], (v[3]-mu)*rs*gg[3]+pp[3]);
  st.z = cvtpk((v[4]-mu)*rs*gg[4]+pp[4], (v[5]-mu)*rs*gg[5]+pp[5]);
  st.w = cvtpk((v[6]-mu)*rs*gg[6]+pp[6], (v[7]-mu)*rs*gg[7]+pp[7]);
  *(uint4*)(y + yoff) = st;
}

// ---- fused embed + layer-0 LN: x = x_in*w + b + pos; lnb = LN(x) ----
__global__ __launch_bounds__(256) void embln_k(
    const float* __restrict__ x_in, const float* __restrict__ w,
    const float* __restrict__ bias, const float* __restrict__ pos,
    const float* __restrict__ g, const float* __restrict__ bet,
    float* __restrict__ x, u16* __restrict__ y) {
  int wid = threadIdx.x >> 6, lane = threadIdx.x & 63;
  int row = blockIdx.x * 4 + wid;
  int t = row & (T_ - 1);
  float xs = x_in[row];
  const float* pr = pos + (size_t)t * DM + lane * 8;
  float4 p0 = *(const float4*)pr;
  float4 p1 = *(const float4*)(pr + 4);
  float4 w0 = *(const float4*)(w + lane * 8);
  float4 w1 = *(const float4*)(w + lane * 8 + 4);
  float4 b0 = *(const float4*)(bias + lane * 8);
  float4 b1 = *(const float4*)(bias + lane * 8 + 4);
  float v[8];
  v[0] = xs * w0.x + b0.x + p0.x; v[1] = xs * w0.y + b0.y + p0.y;
  v[2] = xs * w0.z + b0.z + p0.z; v[3] = xs * w0.w + b0.w + p0.w;
  v[4] = xs * w1.x + b1.x + p1.x; v[5] = xs * w1.y + b1.y + p1.y;
  v[6] = xs * w1.z + b1.z + p1.z; v[7] = xs * w1.w + b1.w + p1.w;
  float* xr = x + (size_t)row * DM + lane * 8;
  ln_finish(xr, v, g, bet, y, (size_t)row * DM + lane * 8, lane, true);
}

// ------- layernorm (+ optional NP bf16 split-K partial-adds into x) ---------
template<int NP>
__global__ __launch_bounds__(256) void ln_k(
    float* __restrict__ x, const u16* __restrict__ P,
    const float* __restrict__ g, const float* __restrict__ bet,
    u16* __restrict__ y) {
  int wid = threadIdx.x >> 6, lane = threadIdx.x & 63;
  int row = blockIdx.x * 4 + wid;
  float* xr = x + (size_t)row * DM + lane * 8;
  float4 a0 = *(const float4*)xr;
  float4 a1 = *(const float4*)(xr + 4);
  float v[8] = {a0.x, a0.y, a0.z, a0.w, a1.x, a1.y, a1.z, a1.w};
  if (NP > 0) {
#pragma unroll
    for (int s = 0; s < NP; s++) {
      const u16* pr = P + (size_t)s * MTOT * DM + (size_t)row * DM + lane * 8;
      uint4 pv = *(const uint4*)pr;
      const u16* px = (const u16*)&pv;
#pragma unroll
      for (int j = 0; j < 8; j++) v[j] += b2f(px[j]);
    }
  }
  ln_finish(xr, v, g, bet, y, (size_t)row * DM + lane * 8, lane, NP > 0);
}

// ---------------- weight convert+transpose: W[K][N] fp32 -> Wt[N][K] bf16 ----
__global__ __launch_bounds__(256) void wconv_k(
    const float* __restrict__ W, u16* __restrict__ Wt, int K, int N) {
  __shared__ float tile[32][33];
  const float* Wl = W + (size_t)blockIdx.z * K * N;
  u16* Wtl = Wt + (size_t)blockIdx.z * K * N;
  int k0 = blockIdx.x * 32, n0 = blockIdx.y * 32;
  int r = threadIdx.x >> 3, c4 = (threadIdx.x & 7) * 4;
  *(float4*)&tile[r][c4] = *(const float4*)(Wl + (size_t)(k0 + r) * N + n0 + c4);
  __syncthreads();
  uint2 st;
  st.x = cvtpk(tile[c4 + 0][r], tile[c4 + 1][r]);
  st.y = cvtpk(tile[c4 + 2][r], tile[c4 + 3][r]);
  *(uint2*)(Wtl + (size_t)(n0 + r) * K + k0 + c4) = st;
}

// ---------------- bf16 MFMA GEMM: C[M,N] = A[M,K] @ Bt[N,K]^T ----------------
// R7 structure: 2-buffer global_load_lds staging, one __syncthreads per step.
// XCD-bijective block swizzle (all grids have nwg%8==0).
// EPI: 0 = bf16 store (cols<scale_cols *= SCALEQ), 1 = Cf += acc,
// 2 = gelu->bf16, 4 = bf16 split-K partial (Cb + z*M*N).
template<int EPI>
__global__ __launch_bounds__(256) void gemm_k(
    const u16* __restrict__ A, const u16* __restrict__ Bt,
    u16* __restrict__ Cb, float* __restrict__ Cf,
    int M, int N, int K, int Kslice, int scale_cols) {
  __shared__ u16 As[2][128][32];
  __shared__ u16 Bs[2][128][32];   // Bs[buf][n][k]
  int tid = threadIdx.x;
  int lane = tid & 63, wid = tid >> 6;
  int wr = wid >> 1, wc = wid & 1;
  // XCD swizzle: contiguous chunk of blocks per XCD (bijective, nwg%8==0)
  int nwg = gridDim.x * gridDim.y;
  int flat = blockIdx.y * gridDim.x + blockIdx.x;
  int swz = (flat & 7) * (nwg >> 3) + (flat >> 3);
  int bx = swz % gridDim.x, by = swz / gridDim.x;
  int m0 = by * 128, n0 = bx * 128;
  int kbeg = blockIdx.z * Kslice;
  if (EPI == 4) Cb += (size_t)blockIdx.z * M * N;
  f32x4 acc[4][4] = {};
  int rsub = lane >> 2, ksub = (lane & 3) * 8;
  const u16* Ab = A  + (size_t)(m0 + wid * 32 + rsub) * K + kbeg + ksub;
  const u16* Bb = Bt + (size_t)(n0 + wid * 32 + rsub) * K + kbeg + ksub;
#define GSTAGE(BUF, KO) { \
    gload_lds(Ab + (KO), &As[BUF][wid * 32][0]); \
    gload_lds(Ab + (size_t)16 * K + (KO), &As[BUF][wid * 32 + 16][0]); \
    gload_lds(Bb + (KO), &Bs[BUF][wid * 32][0]); \
    gload_lds(Bb + (size_t)16 * K + (KO), &Bs[BUF][wid * 32 + 16][0]); }
  GSTAGE(0, 0);
  __syncthreads();
  int r = lane & 15, kc = (lane >> 4) * 8;
  for (int k0 = 0; k0 < Kslice; k0 += 32) {
    int cur = (k0 >> 5) & 1;
    if (k0 + 32 < Kslice) GSTAGE(cur ^ 1, k0 + 32);
    bf16x8 af[4], bfr[4];
#pragma unroll
    for (int m = 0; m < 4; m++) af[m]  = *(const bf16x8*)&As[cur][wr*64 + m*16 + r][kc];
#pragma unroll
    for (int n = 0; n < 4; n++) bfr[n] = *(const bf16x8*)&Bs[cur][wc*64 + n*16 + r][kc];
#pragma unroll
    for (int m = 0; m < 4; m++)
#pragma unroll
      for (int n = 0; n < 4; n++)
        acc[m][n] = __builtin_amdgcn_mfma_f32_16x16x32_bf16(af[m], bfr[n], acc[m][n], 0, 0, 0);
    __syncthreads();
  }
  int r4 = (lane >> 4) * 4, cN = lane & 15;
#pragma unroll
  for (int m = 0; m < 4; m++) {
#pragma unroll
    for (int n = 0; n < 4; n++) {
      int col = n0 + wc*64 + n*16 + cN;
#pragma unroll
      for (int i = 0; i < 4; i++) {
        int row = m0 + wr*64 + m*16 + r4 + i;
        size_t off = (size_t)row * N + col;
        float v = acc[m][n][i];
        if (EPI == 0) {
          if (col < scale_cols) v *= SCALEQ;
          Cb[off] = f2b(v);
        } else if (EPI == 1) {
          Cf[off] += v;
        } else if (EPI == 4) {
          Cb[off] = f2b(v);
        } else {
          float e = EXP2(v * (2.3022082f + 0.10294324f * v * v));
          Cb[off] = f2b(v * (1.0f - RCP(e + 1.0f)));
        }
      }
    }
  }
}

// permlane32_swap: one instr yields BOTH PV fragment words for a lane-half pair
#if __has_builtin(__builtin_amdgcn_permlane32_swap)
#define PLSWAP(A, B, O0, O1) { \
    u32x2 r_ = __builtin_amdgcn_permlane32_swap((A), (B), false, false); \
    O0 = r_.x; O1 = r_.y; }
#else
#define PLSWAP(A, B, O0, O1) { \
    u32 as_ = __shfl_xor((u32)(A), 32), bs_ = __shfl_xor((u32)(B), 32); \
    O0 = hh ? bs_ : (A); O1 = hh ? (B) : as_; }
#endif

// ---------------- MFMA causal flash attention, uniform 8-tile chunks --------
// R7/R9 structure (measured 82us): double-buffered 32KB LDS, reg-staged K+V,
// ONE __syncthreads per tile, next tile's loads issued after the barrier.
__global__ __launch_bounds__(256) void attn_k(const u16* __restrict__ qkv,
                                              u16* __restrict__ Opart,
                                              float* __restrict__ ml) {
  __shared__ u16 Ks[2][64 * 64];
  __shared__ u16 Vt[2][64 * 64];
  int tid = threadIdx.x;
  int w = tid >> 6, l = tid & 63;
  int hh = l >> 5, c = l & 31;
  int flat = blockIdx.y * 144 + blockIdx.x;
  int swz = (flat & 7) * 288 + (flat >> 3);      // 2304/8 = 288
  int bh = swz / 144, slot = swz - bh * 144;
  int g = 0;
  while (2 * (g + 1) * (g + 2) <= slot) g++;     // group index 0..7
  int s2 = slot - 2 * g * (g + 1);
  int qb = 4 * g + s2 / (g + 1);
  int ck = s2 - (s2 / (g + 1)) * (g + 1);
  int ntot = 2 * qb + 2;
  int kt0 = ck * 8;
  int kt1 = kt0 + 8 < ntot ? kt0 + 8 : ntot;
  int b = bh >> 3, hd = bh & 7;
  int q0w = qb * 128 + w * 32;
  int q_abs = q0w + c;
  size_t base = (size_t)b * T_ * 1536;
  bf16x8 qf[4];
  const u16* qp = qkv + base + (size_t)q_abs * 1536 + hd * 64 + hh * 8;
#pragma unroll
  for (int kk = 0; kk < 4; kk++) qf[kk] = *(const bf16x8*)(qp + kk * 16);
  f32x16 oa0 = {}, oa1 = {};
  float m_run = -1e30f, l_run = 0.f;
  // staging: thread handles kv-row pair (2sp, 2sp+1), d-chunk d8..d8+7
  int sp = tid >> 3, d8 = (tid & 7) * 8;
  int r0 = sp * 2, r1 = r0 + 1;
  const u16* kvbase = qkv + base + DM + hd * 64 + d8;
  uint4 kreg0, kreg1, vreg0, vreg1;
#define AGLOAD(KT) { \
    const u16* s0_ = kvbase + (size_t)((KT) * 64 + r0) * 1536; \
    kreg0 = *(const uint4*)s0_; vreg0 = *(const uint4*)(s0_ + DM); \
    const u16* s1_ = s0_ + 1536; \
    kreg1 = *(const uint4*)s1_; vreg1 = *(const uint4*)(s1_ + DM); }
  AGLOAD(kt0);
  for (int kt = kt0; kt < kt1; kt++) {
    u16* Kb = Ks[kt & 1];
    u16* Vb = Vt[kt & 1];
    // ds_write staged regs (K row-major swizzled; V transposed, kv-pairs packed)
    *(uint4*)&Kb[lsw(r0, d8)] = kreg0;
    *(uint4*)&Kb[lsw(r1, d8)] = kreg1;
    {
      const u16* v0 = (const u16*)&vreg0;
      const u16* v1 = (const u16*)&vreg1;
#pragma unroll
      for (int j = 0; j < 8; j++) {
        u32 pw = (u32)v0[j] | ((u32)v1[j] << 16);
        *(u32*)&Vb[lsw(d8 + j, r0)] = pw;
      }
    }
    __syncthreads();                   // writes visible; prev-tile reads done
    if (kt + 1 < kt1) AGLOAD(kt + 1);  // in flight under this tile's compute
    if (kt * 64 > q0w + 31) continue;  // fully masked for this wave
    bool needMask = (kt * 64 + 63 > q0w);
    f32x16 sa0 = {}, sa1 = {};
    __builtin_amdgcn_s_setprio(1);
#pragma unroll
    for (int kk = 0; kk < 4; kk++) {
      bf16x8 ka  = *(const bf16x8*)&Kb[lsw(c,      kk * 16 + hh * 8)];
      bf16x8 kb2 = *(const bf16x8*)&Kb[lsw(32 + c, kk * 16 + hh * 8)];
      sa0 = __builtin_amdgcn_mfma_f32_32x32x16_bf16(ka,  qf[kk], sa0, 0, 0, 0);
      sa1 = __builtin_amdgcn_mfma_f32_32x32x16_bf16(kb2, qf[kk], sa1, 0, 0, 0);
    }
    __builtin_amdgcn_s_setprio(0);
    if (needMask) {
#pragma unroll
      for (int gi = 0; gi < 4; gi++)
#pragma unroll
        for (int i = 0; i < 4; i++) {
          int krow = kt * 64 + gi * 8 + hh * 4 + i;
          if (krow > q_abs)      sa0[gi * 4 + i] = -1e30f;
          if (krow + 32 > q_abs) sa1[gi * 4 + i] = -1e30f;
        }
    }
    // max tree (depth ~5)
    float t[8];
#pragma unroll
    for (int r = 0; r < 8; r++)
      t[r] = fmaxf(fmaxf(sa0[r], sa0[r + 8]), fmaxf(sa1[r], sa1[r + 8]));
    float pm = fmaxf(fmaxf(fmaxf(t[0], t[1]), fmaxf(t[2], t[3])),
                     fmaxf(fmaxf(t[4], t[5]), fmaxf(t[6], t[7])));
    pm = fmaxf(pm, __shfl_xor(pm, 32));
    if (!__all(pm - m_run <= 8.0f)) {
      float mnew = fmaxf(m_run, pm);
      float corr = EXP2(m_run - mnew);
      l_run *= corr;
#pragma unroll
      for (int r = 0; r < 16; r++) { oa0[r] *= corr; oa1[r] *= corr; }
      m_run = mnew;
    }
    float sarr[16];
#pragma unroll
    for (int r = 0; r < 16; r++) {
      float e0 = EXP2(sa0[r] - m_run); sa0[r] = e0;
      float e1 = EXP2(sa1[r] - m_run); sa1[r] = e1;
      sarr[r] = e0 + e1;
    }
#pragma unroll
    for (int r = 0; r < 8; r++) sarr[r] += sarr[r + 8];
#pragma unroll
    for (int r = 0; r < 4; r++) sarr[r] += sarr[r + 4];
    float lsum = (sarr[0] + sarr[1]) + (sarr[2] + sarr[3]);
    lsum += __shfl_xor(lsum, 32);
    l_run += lsum;
    // pack P^T -> bf16 words
    u32 Aw[8], Bw_[8];
#pragma unroll
    for (int r2 = 0; r2 < 4; r2++) {
      Aw[r2]      = cvtpk(sa0[4 * r2 + 0], sa0[4 * r2 + 1]);
      Bw_[r2]     = cvtpk(sa0[4 * r2 + 2], sa0[4 * r2 + 3]);
      Aw[4 + r2]  = cvtpk(sa1[4 * r2 + 0], sa1[4 * r2 + 1]);
      Bw_[4 + r2] = cvtpk(sa1[4 * r2 + 2], sa1[4 * r2 + 3]);
    }
    // O^T += V^T . P^T   (permlane32_swap builds both fragment halves)
    __builtin_amdgcn_s_setprio(1);
#pragma unroll
    for (int ks = 0; ks < 4; ks++) {
      int mo = (ks >> 1) * 4;
      int r2e = mo + 2 * (ks & 1), r2o = r2e + 1;
      union { u32 wd[4]; bf16x8 v; } u;
      PLSWAP(Aw[r2e], Aw[r2o], u.wd[0], u.wd[2]);
      PLSWAP(Bw_[r2e], Bw_[r2o], u.wd[1], u.wd[3]);
      bf16x8 va = *(const bf16x8*)&Vb[lsw(c,      ks * 16 + hh * 8)];
      bf16x8 vb = *(const bf16x8*)&Vb[lsw(32 + c, ks * 16 + hh * 8)];
      oa0 = __builtin_amdgcn_mfma_f32_32x32x16_bf16(va, u.v, oa0, 0, 0, 0);
      oa1 = __builtin_amdgcn_mfma_f32_32x32x16_bf16(vb, u.v, oa1, 0, 0, 0);
    }
    __builtin_amdgcn_s_setprio(0);
  }
  // write unnormalized partial
  int sidx = bh * 144 + slot;
  u16* op = Opart + ((size_t)sidx * 128 + w * 32 + c) * 64;
#pragma unroll
  for (int gi = 0; gi < 4; gi++) {
    uint2 s0, s1;
    s0.x = cvtpk(oa0[4*gi+0], oa0[4*gi+1]);
    s0.y = cvtpk(oa0[4*gi+2], oa0[4*gi+3]);
    s1.x = cvtpk(oa1[4*gi+0], oa1[4*gi+1]);
    s1.y = cvtpk(oa1[4*gi+2], oa1[4*gi+3]);
    int d0 = gi * 8 + hh * 4;
    *(uint2*)(op + d0)      = s0;
    *(uint2*)(op + 32 + d0) = s1;
  }
  if (hh == 0) {
    float2 p; p.x = m_run; p.y = l_run;
    *(float2*)&ml[((size_t)sidx * 128 + w * 32 + c) * 2] = p;
  }
}

// ---------------- combine partials -> attno (4 d-elems per thread) ----------
__global__ __launch_bounds__(256) void comb_k(
    const u16* __restrict__ Opart, const float* __restrict__ ml,
    u16* __restrict__ attno) {
  int gi = blockIdx.x * 256 + threadIdx.x;     // over 16*4096*16
  int d4 = (gi & 15) * 4;
  int bhq = gi >> 4;
  int bh = bhq >> 12, q = bhq & 4095;
  int qb = q >> 7, ri = q & 127;
  int g = qb >> 2;
  int nc = g + 1;
  int bs = 2 * g * (g + 1) + (qb & 3) * (g + 1);
  int s0 = bh * 144 + bs;
  float M = -1e30f;
  for (int cc = 0; cc < nc; cc++)
    M = fmaxf(M, ml[((size_t)(s0 + cc) * 128 + ri) * 2]);
  float O0 = 0.f, O1 = 0.f, O2 = 0.f, O3 = 0.f, L = 0.f;
  for (int cc = 0; cc < nc; cc++) {
    float2 p = *(const float2*)&ml[((size_t)(s0 + cc) * 128 + ri) * 2];
    float wgt = EXP2(p.x - M);
    L += p.y * wgt;
    uint2 ov = *(const uint2*)&Opart[((size_t)(s0 + cc) * 128 + ri) * 64 + d4];
    const u16* opx = (const u16*)&ov;
    O0 += b2f(opx[0]) * wgt; O1 += b2f(opx[1]) * wgt;
    O2 += b2f(opx[2]) * wgt; O3 += b2f(opx[3]) * wgt;
  }
  float invL = 1.0f / L;
  int b = bh >> 3, hd = bh & 7;
  uint2 st;
  st.x = cvtpk(O0 * invL, O1 * invL);
  st.y = cvtpk(O2 * invL, O3 * invL);
  *(uint2*)&attno[((size_t)b * T_ + q) * DM + hd * 64 + d4] = st;
}

// ---------------- head: out = lnf(bf16) @ head_w + head_b, N=64 ----------------
__global__ __launch_bounds__(256) void head_k(
    const u16* __restrict__ xb, const float* __restrict__ W,
    const float* __restrict__ bias, float* __restrict__ out) {
  int wid = threadIdx.x >> 6, lane = threadIdx.x & 63;
  int row = blockIdx.x * 4 + wid;
  const u16* xr = xb + (size_t)row * DM;
  float a0 = 0.f, a1 = 0.f, a2 = 0.f, a3 = 0.f;
  for (int d = 0; d < DM; d += 8) {
    uint4 xv = *(const uint4*)(xr + d);
    const u16* xp = (const u16*)&xv;
    const float* Wp = W + (size_t)d * 64 + lane;
    a0 += b2f(xp[0]) * Wp[0];
    a1 += b2f(xp[1]) * Wp[64];
    a2 += b2f(xp[2]) * Wp[128];
    a3 += b2f(xp[3]) * Wp[192];
    a0 += b2f(xp[4]) * Wp[256];
    a1 += b2f(xp[5]) * Wp[320];
    a2 += b2f(xp[6]) * Wp[384];
    a3 += b2f(xp[7]) * Wp[448];
  }
  out[(size_t)row * 64 + lane] = a0 + a1 + a2 + a3 + bias[lane];
}

extern "C" void kernel_launch(void* const* d_in, const int* in_sizes, int n_in,
                              void* d_out, int out_size, void* d_ws, size_t ws_size,
                              hipStream_t stream) {
  (void)in_sizes; (void)n_in; (void)out_size; (void)ws_size;
  const float* x_in  = (const float*)d_in[0];
  const float* inp_w = (const float*)d_in[1];
  const float* inp_b = (const float*)d_in[2];
  const float* pos   = (const float*)d_in[3];
  const float* ln1g  = (const float*)d_in[4];
  const float* ln1b  = (const float*)d_in[5];
  const float* qkvw  = (const float*)d_in[6];
  const float* projw = (const float*)d_in[7];
  const float* ln2g  = (const float*)d_in[8];
  const float* ln2b  = (const float*)d_in[9];
  const float* fc1w  = (const float*)d_in[10];
  const float* fc2w  = (const float*)d_in[11];
  const float* lnfg  = (const float*)d_in[12];
  const float* lnfb  = (const float*)d_in[13];
  const float* headw = (const float*)d_in[14];
  const float* headb = (const float*)d_in[15];

  char* ws = (char*)d_ws;
  size_t off = 0;
  float* x     = (float*)(ws + off); off += (size_t)MTOT * DM * 4;
  u16*  lnb    = (u16*)(ws + off);   off += (size_t)MTOT * DM * 2;
  u16*  qkvb   = (u16*)(ws + off);   off += (size_t)MTOT * 3 * DM * 2;
  u16*  attno  = (u16*)(ws + off);   off += (size_t)MTOT * DM * 2;
  u16*  ff     = qkvb;  // reuses qkv+attno regions
  u16*  qkvt   = (u16*)(ws + off);   off += (size_t)4 * DM * 3 * DM * 2;
  u16*  projt  = (u16*)(ws + off);   off += (size_t)4 * DM * DM * 2;
  u16*  fc1t   = (u16*)(ws + off);   off += (size_t)4 * DM * DFF * 2;
  u16*  fc2t   = (u16*)(ws + off);   off += (size_t)4 * DFF * DM * 2;
  // shared scratch, time-multiplexed:
  //   attn..comb : Opart (37.75MB) + ml (2.36MB)
  //   proj..ln2  : proj split-K2 bf16 partials (16.8MB)
  //   fc2..ln1'  : fc2  split-K2 bf16 partials (16.8MB)
  char* shared = ws + off;
  u16*  Opart  = (u16*)shared;
  float* mlbuf = (float*)(shared + (size_t)16 * 144 * 128 * 64 * 2);
  u16*  fcp    = (u16*)shared;

  wconv_k<<<dim3(16, 48, 4), 256, 0, stream>>>(qkvw,  qkvt, DM, 3 * DM);
  wconv_k<<<dim3(16, 16, 4), 256, 0, stream>>>(projw, projt, DM, DM);
  wconv_k<<<dim3(16, 64, 4), 256, 0, stream>>>(fc1w,  fc1t, DM, DFF);
  wconv_k<<<dim3(64, 16, 4), 256, 0, stream>>>(fc2w,  fc2t, DFF, DM);

  for (int ly = 0; ly < 4; ly++) {
    if (ly == 0)
      embln_k<<<MTOT / 4, 256, 0, stream>>>(x_in, inp_w, inp_b, pos,
                                            ln1g, ln1b, x, lnb);
    else
      ln_k<2><<<MTOT / 4, 256, 0, stream>>>(x, fcp, ln1g + ly * DM, ln1b + ly * DM, lnb);
    gemm_k<0><<<dim3(12, 64), 256, 0, stream>>>(lnb, qkvt + (size_t)ly * DM * 3 * DM,
                                                qkvb, nullptr, MTOT, 3 * DM, DM, DM, DM);
    attn_k<<<dim3(144, 16), 256, 0, stream>>>(qkvb, Opart, mlbuf);
    comb_k<<<(16 * 4096 * 16) / 256, 256, 0, stream>>>(Opart, mlbuf, attno);
    gemm_k<4><<<dim3(4, 64, 2), 256, 0, stream>>>(attno, projt + (size_t)ly * DM * DM,
                                                  fcp, nullptr, MTOT, DM, DM, DM / 2, 0);
    ln_k<2><<<MTOT / 4, 256, 0, stream>>>(x, fcp, ln2g + ly * DM, ln2b + ly * DM, lnb);
    gemm_k<2><<<dim3(16, 64), 256, 0, stream>>>(lnb, fc1t + (size_t)ly * DM * DFF,
                                                ff, nullptr, MTOT, DFF, DM, DM, 0);
    gemm_k<4><<<dim3(4, 64, 2), 256, 0, stream>>>(ff, fc2t + (size_t)ly * DFF * DM,
                                                  fcp, nullptr, MTOT, DM, DFF, DFF / 2, 0);
  }
  ln_k<2><<<MTOT / 4, 256, 0, stream>>>(x, fcp, lnfg, lnfb, lnb);
  head_k<<<MTOT / 4, 256, 0, stream>>>(lnb, headw, headb, (float*)d_out);
}